// Round 1
// baseline (303.680 us; speedup 1.0000x reference)
//
#include <hip/hip_runtime.h>
#include <hip/hip_bf16.h>
#include <math.h>

typedef __bf16 bf16_8 __attribute__((ext_vector_type(8)));
typedef float f32x4 __attribute__((ext_vector_type(4)));

#define NDIM 1024
#define BM 128
#define BN 128
#define BK 32
#define BSTRIDE 40  // padded LDS row stride for B tile (banks spread: gcd(20,32)=4)

__device__ static inline void async_copy16(const void* g, void* l) {
  __builtin_amdgcn_global_load_lds(
      (__attribute__((address_space(1))) void*)g,
      (__attribute__((address_space(3))) void*)l, 16, 0, 0);
}

// C[k][j] = s(k) * cos(pi * k * (2j+1) / 2048), s(0)=1/32, s(k)=sqrt(2)/32
__global__ void gen_dct_mat(__bf16* __restrict__ C) {
  int idx = blockIdx.x * blockDim.x + threadIdx.x;
  int k = idx >> 10;
  int j = idx & 1023;
  int t = (k * (2 * j + 1)) & 4095;  // exact phase reduction mod 2*pi
  float ang = (float)t * 1.5339807878856412e-3f;  // pi/2048
  float s = (k == 0) ? 0.03125f : 0.04419417382415922f;
  C[idx] = (__bf16)(s * cosf(ang));
}

__global__ __launch_bounds__(256) void dct_gemm(
    const float* __restrict__ x, const __bf16* __restrict__ A,
    float* __restrict__ out) {
  __shared__ __align__(64) __bf16 Asm[BM * BK];        // [m][k], 8 KB
  __shared__ __align__(64) __bf16 Bsm[BN * BSTRIDE];   // [c][k], 10 KB

  const int t = threadIdx.x;
  const int wave = t >> 6;
  const int lane = t & 63;
  const int bb = blockIdx.z;
  const int m0 = blockIdx.y * BM;
  const int n0 = blockIdx.x * BN;

  // ---- A staging via global_load_lds (wave-uniform LDS base + lane*16) ----
  // issue i (0/1): wave w covers rows [i*64 + w*16, +16); lane l -> row += l/4, col = (l%4)*8
  const __bf16* Ag0 =
      A + (size_t)(m0 + wave * 16 + (lane >> 2)) * NDIM + ((lane & 3) * 8);
  const __bf16* Ag1 = Ag0 + (size_t)64 * NDIM;
  __bf16* Al0 = Asm + (wave * 16) * BK;
  __bf16* Al1 = Asm + (64 + wave * 16) * BK;

  // ---- B staging: fused fp32 load + cvt + transpose into [c][k] ----
  const int bc = t & 127;   // local column c
  const int bjg = t >> 7;   // j-half: 0 -> k 0..15, 1 -> k 16..31
  const float* xs =
      x + (size_t)bb * (NDIM * NDIM) + (size_t)(bjg * 16) * NDIM + (n0 + bc);
  bf16_8* bs0 = (bf16_8*)(Bsm + bc * BSTRIDE + bjg * 16);
  bf16_8* bs1 = (bf16_8*)(Bsm + bc * BSTRIDE + bjg * 16 + 8);

  // fragment addressing: A[m = lane&15][k = (lane>>4)*8 + q]
  const int row16 = lane & 15;
  const int kq8 = (lane >> 4) * 8;
  const int wm = (wave & 1) * 64;
  const int wn = (wave >> 1) * 64;

  f32x4 acc[4][4] = {};

  for (int k0 = 0; k0 < NDIM; k0 += BK) {
    __syncthreads();  // previous tile's compute done before overwrite
    async_copy16(Ag0 + k0, Al0);
    async_copy16(Ag1 + k0, Al1);

    const float* xp = xs + (size_t)k0 * NDIM;
    bf16_8 v0, v1;
#pragma unroll
    for (int q = 0; q < 8; q++) {
      v0[q] = (__bf16)xp[(size_t)q * NDIM];
      v1[q] = (__bf16)xp[(size_t)(q + 8) * NDIM];
    }
    *bs0 = v0;
    *bs1 = v1;
    __syncthreads();  // drains vmcnt (DMA) + lgkmcnt (ds_write)

    bf16_8 af[4], bfr[4];
#pragma unroll
    for (int i = 0; i < 4; i++)
      af[i] = *(const bf16_8*)(Asm + (wm + i * 16 + row16) * BK + kq8);
#pragma unroll
    for (int j = 0; j < 4; j++)
      bfr[j] = *(const bf16_8*)(Bsm + (wn + j * 16 + row16) * BSTRIDE + kq8);
#pragma unroll
    for (int i = 0; i < 4; i++)
#pragma unroll
      for (int j = 0; j < 4; j++)
        acc[i][j] = __builtin_amdgcn_mfma_f32_16x16x32_bf16(af[i], bfr[j],
                                                            acc[i][j], 0, 0, 0);
  }

  // ---- epilogue: C/D layout col = lane&15, row = (lane>>4)*4 + reg ----
  float* ob = out + (size_t)bb * (NDIM * NDIM);
  const int rbase = (lane >> 4) * 4;
  const int cofs = lane & 15;
#pragma unroll
  for (int i = 0; i < 4; i++) {
#pragma unroll
    for (int r = 0; r < 4; r++) {
      int row = m0 + wm + i * 16 + rbase + r;
#pragma unroll
      for (int j = 0; j < 4; j++) {
        int col = n0 + wn + j * 16 + cofs;
        ob[(size_t)row * NDIM + col] = acc[i][j][r];
      }
    }
  }
}

extern "C" void kernel_launch(void* const* d_in, const int* in_sizes, int n_in,
                              void* d_out, int out_size, void* d_ws,
                              size_t ws_size, hipStream_t stream) {
  const float* x = (const float*)d_in[0];
  float* out = (float*)d_out;
  __bf16* Cmat = (__bf16*)d_ws;  // 1024*1024 bf16 = 2 MB

  gen_dct_mat<<<dim3((NDIM * NDIM) / 256), dim3(256), 0, stream>>>(Cmat);

  dim3 grid(NDIM / BN, NDIM / BM, 32);
  dct_gemm<<<grid, dim3(256), 0, stream>>>(x, Cmat, out);
}